// Round 4
// baseline (74.855 us; speedup 1.0000x reference)
//
#include <hip/hip_runtime.h>
#include <hip/hip_fp16.h>

#define DIM 128
#define GROWS 32

typedef _Float16 f16x8 __attribute__((ext_vector_type(8)));
typedef float f32x4 __attribute__((ext_vector_type(4)));

// ---------- Kernel 1 (fused): qtab = int8_rowquant(emb @ W), scales[r] =
// rowmax/127, gmax = table absmax (atomicMax on float bits), via fp16 MFMA
// + segment-boundary scan in the same launch.
//
// MFMA fragment layouts (mfma_f32_16x16x32_f16, harness-verified round 1):
//   A (16x32): row = lane&15, k = (lane>>4)*8 + i  -> 8 contiguous floats
//   B (32x16): col = lane&15, k = (lane>>4)*8 + i  -> stride-DIM scalars
//   D (16x16): col = lane&15, row = (lane>>4)*4 + reg
__global__ __launch_bounds__(256, 2) void prep_kernel(
    const int* __restrict__ segs, int* __restrict__ seg_start,
    const float* __restrict__ emb, const float* __restrict__ W,
    signed char* __restrict__ qtab, float* __restrict__ scales,
    unsigned* __restrict__ gbits, int T, int B, int V, int mtiles,
    int nTrans) {
  if ((int)blockIdx.x >= nTrans) {
    // ---- boundaries: seg_start[s] = lower_bound(segs, s), streaming ----
    const int i = (blockIdx.x - nTrans) * 256 + threadIdx.x;
    if (i > T) return;
    const int cur = (i < T) ? segs[i] : B;
    const int prev = (i > 0) ? segs[i - 1] : -1;
    for (int s = prev + 1; s <= cur; ++s) seg_start[s] = i;
    return;
  }

  const int wid = blockIdx.x * 4 + (threadIdx.x >> 6);
  const int nwaves = nTrans * 4;
  const int lane = threadIdx.x & 63;
  const int lr = lane & 15;   // A-row / B-col / D-col
  const int lg = lane >> 4;   // k-group (A/B), row-group (D)

  // Preload all B fragments of W (fp32 -> fp16). W is 64KB, L1/L2-hot.
  f16x8 bfrag[8][4];
#pragma unroll
  for (int n = 0; n < 8; ++n)
#pragma unroll
    for (int s = 0; s < 4; ++s) {
      const float* wp = W + (size_t)(s * 32 + lg * 8) * DIM + n * 16 + lr;
      f16x8 f;
#pragma unroll
      for (int i = 0; i < 8; ++i) f[i] = (_Float16)wp[(size_t)i * DIM];
      bfrag[n][s] = f;
    }

  float wmax = 0.f;  // per-thread running max of row maxes

  for (int mt = wid; mt < mtiles; mt += nwaves) {
    const float* arow = emb + (size_t)(mt * 16 + lr) * DIM;
    f16x8 afrag[4];
#pragma unroll
    for (int s = 0; s < 4; ++s) {
      const float4 a0 = *reinterpret_cast<const float4*>(arow + s * 32 + lg * 8);
      const float4 a1 = *reinterpret_cast<const float4*>(arow + s * 32 + lg * 8 + 4);
      f16x8 f;
      f[0] = (_Float16)a0.x; f[1] = (_Float16)a0.y;
      f[2] = (_Float16)a0.z; f[3] = (_Float16)a0.w;
      f[4] = (_Float16)a1.x; f[5] = (_Float16)a1.y;
      f[6] = (_Float16)a1.z; f[7] = (_Float16)a1.w;
      afrag[s] = f;
    }
    f32x4 accs[8];
#pragma unroll
    for (int n = 0; n < 8; ++n) {
      f32x4 a = {0.f, 0.f, 0.f, 0.f};
#pragma unroll
      for (int s = 0; s < 4; ++s)
        a = __builtin_amdgcn_mfma_f32_16x16x32_f16(afrag[s], bfrag[n][s],
                                                   a, 0, 0, 0);
      accs[n] = a;
    }
    // per-row absmax: in-lane over n, then across the 16 lr lanes
    const int r0 = mt * 16 + lg * 4;
    float inv[4];
#pragma unroll
    for (int j = 0; j < 4; ++j) {
      float mm = fabsf(accs[0][j]);
#pragma unroll
      for (int n = 1; n < 8; ++n) mm = fmaxf(mm, fabsf(accs[n][j]));
      mm = fmaxf(mm, __shfl_xor(mm, 1));
      mm = fmaxf(mm, __shfl_xor(mm, 2));
      mm = fmaxf(mm, __shfl_xor(mm, 4));
      mm = fmaxf(mm, __shfl_xor(mm, 8));
      inv[j] = (mm > 0.f) ? 127.f / mm : 0.f;
      wmax = fmaxf(wmax, mm);
      if (lr == 0) scales[r0 + j] = mm * (1.f / 127.f);
    }
#pragma unroll
    for (int n = 0; n < 8; ++n)
#pragma unroll
      for (int j = 0; j < 4; ++j)
        qtab[(size_t)(r0 + j) * DIM + n * 16 + lr] =
            (signed char)(int)rintf(accs[n][j] * inv[j]);
  }

  if (lr == 0 && wmax > 0.f)
    atomicMax(gbits, __float_as_uint(wmax));  // positive floats: uint order ok

  // tail rows if V % 16 != 0 (dead for V=100000, kept for safety)
  const int tailStart = mtiles * 16;
  if (wid == 0 && tailStart < V) {
    const int c2 = lane * 2;
    for (int r = tailStart; r < V; ++r) {
      float s0 = 0.f, s1 = 0.f;
      for (int k = 0; k < DIM; ++k) {
        const float e = emb[(size_t)r * DIM + k];
        s0 = fmaf(e, W[(size_t)k * DIM + c2], s0);
        s1 = fmaf(e, W[(size_t)k * DIM + c2 + 1], s1);
      }
      float mm = fmaxf(fabsf(s0), fabsf(s1));
      mm = fmaxf(mm, __shfl_xor(mm, 1));
      mm = fmaxf(mm, __shfl_xor(mm, 2));
      mm = fmaxf(mm, __shfl_xor(mm, 4));
      mm = fmaxf(mm, __shfl_xor(mm, 8));
      mm = fmaxf(mm, __shfl_xor(mm, 16));
      mm = fmaxf(mm, __shfl_xor(mm, 32));
      const float iv = (mm > 0.f) ? 127.f / mm : 0.f;
      if (lane == 0) {
        scales[r] = mm * (1.f / 127.f);
        if (mm > 0.f) atomicMax(gbits, __float_as_uint(mm));
      }
      qtab[(size_t)r * DIM + c2] = (signed char)(int)rintf(s0 * iv);
      qtab[(size_t)r * DIM + c2 + 1] = (signed char)(int)rintf(s1 * iv);
    }
  }
}

// ---------- Kernel 1b: in-place requant to global-scale biased u8 ---------
// u8 = round(q * scales[row] * 127/gmax) + 128. ratio <= 1 so result is in
// [1,255]; streaming, each thread owns its 4 bytes -> in-place safe.
__global__ __launch_bounds__(256) void requant_kernel(
    signed char* __restrict__ qtab, const float* __restrict__ scales,
    const unsigned* __restrict__ gbits, int n4) {
  const float gmax = __uint_as_float(*gbits);
  const float rg = (gmax > 0.f) ? 127.f / gmax : 0.f;
  int i = blockIdx.x * 256 + threadIdx.x;
  const int stride = gridDim.x * 256;
  unsigned* q32 = reinterpret_cast<unsigned*>(qtab);
  for (; i < n4; i += stride) {
    const unsigned w = q32[i];
    const float ratio = scales[i >> 5] * rg;  // 32 words per 128-dim row
    const int b0 = (int)(w << 24) >> 24;
    const int b1 = (int)(w << 16) >> 24;
    const int b2 = (int)(w << 8) >> 24;
    const int b3 = (int)w >> 24;
    const unsigned u0 = (unsigned)((int)rintf(b0 * ratio) + 128) & 0xFFu;
    const unsigned u1 = (unsigned)((int)rintf(b1 * ratio) + 128) & 0xFFu;
    const unsigned u2 = (unsigned)((int)rintf(b2 * ratio) + 128) & 0xFFu;
    const unsigned u3 = (unsigned)((int)rintf(b3 * ratio) + 128) & 0xFFu;
    q32[i] = u0 | (u1 << 8) | (u2 << 16) | (u3 << 24);
  }
}

// ---------- Kernel 2: u8 gather + segment sum + bias + relu ---------------
// One wave per segment (4 waves/block, 8 waves/EU pinned). 32-row clamped
// batches: 8 uint2 loads in flight (16 lanes x 8B = one 128B row per lane-
// quad). NO scale gather (global scale). Accumulate packed u16
// (SIMD-in-register, bias-128 u8; per-batch field max 32*255 < 65535),
// spill to u32 per batch. Masked slots become 0x80808080 (pure bias),
// corrected by -128*slots at the end. Epilogue: out = gs*(tot-corr)+b.

__global__ __launch_bounds__(256, 8) void segsum_u8(
    const int* __restrict__ tokens, const unsigned char* __restrict__ qtab,
    const int* __restrict__ seg_start, const unsigned* __restrict__ gbits,
    const float* __restrict__ bias, float* __restrict__ out, int B) {
  const int seg = blockIdx.x * 4 + (threadIdx.x >> 6);
  if (seg >= B) return;
  const int lane = threadIdx.x & 63;
  const int g = lane >> 4;            // row-in-quad 0..3
  const int c8 = (lane & 15) * 8;     // byte offset of this lane's 8 dims
  const int lo = seg_start[seg], hi = seg_start[seg + 1];
  const int cnt = hi - lo;
  const int last = hi - 1;
  unsigned tot[8] = {0u, 0u, 0u, 0u, 0u, 0u, 0u, 0u};

  const int nbatch = (cnt + 31) >> 5;
  for (int b = 0; b < nbatch; ++b) {
    const int base = lo + (b << 5);
    unsigned pa = 0u, pb = 0u, pc = 0u, pd = 0u;
#define LQ(u)                                                              \
  const int i##u = base + 4 * u + g;                                       \
  const int t##u = tokens[min(i##u, last)];                                \
  uint2 r##u = *reinterpret_cast<const uint2*>(                            \
      qtab + (size_t)t##u * DIM + c8);                                     \
  if (i##u > last) { r##u.x = 0x80808080u; r##u.y = 0x80808080u; }
    LQ(0) LQ(1) LQ(2) LQ(3) LQ(4) LQ(5) LQ(6) LQ(7)
#define AQ(u)                                                              \
  pa += r##u.x & 0x00FF00FFu; pb += (r##u.x >> 8) & 0x00FF00FFu;           \
  pc += r##u.y & 0x00FF00FFu; pd += (r##u.y >> 8) & 0x00FF00FFu;
    AQ(0) AQ(1) AQ(2) AQ(3) AQ(4) AQ(5) AQ(6) AQ(7)
#undef AQ
#undef LQ
    tot[0] += pa & 0xFFFFu; tot[2] += pa >> 16;
    tot[1] += pb & 0xFFFFu; tot[3] += pb >> 16;
    tot[4] += pc & 0xFFFFu; tot[6] += pc >> 16;
    tot[5] += pd & 0xFFFFu; tot[7] += pd >> 16;
  }
#pragma unroll
  for (int k = 0; k < 8; ++k) {
    tot[k] += (unsigned)__shfl_xor((int)tot[k], 16);
    tot[k] += (unsigned)__shfl_xor((int)tot[k], 32);
  }
  if (g == 0) {
    const float gs = __uint_as_float(*gbits) * (1.f / 127.f);
    const float corr = 128.f * (float)(nbatch << 5);
    float* op = out + (size_t)seg * DIM + c8;
    const float4 b0 = *reinterpret_cast<const float4*>(bias + c8);
    const float4 b1 = *reinterpret_cast<const float4*>(bias + c8 + 4);
    float4 o0, o1;
    o0.x = fmaxf(fmaf(gs, (float)tot[0] - corr, b0.x), 0.f);
    o0.y = fmaxf(fmaf(gs, (float)tot[1] - corr, b0.y), 0.f);
    o0.z = fmaxf(fmaf(gs, (float)tot[2] - corr, b0.z), 0.f);
    o0.w = fmaxf(fmaf(gs, (float)tot[3] - corr, b0.w), 0.f);
    o1.x = fmaxf(fmaf(gs, (float)tot[4] - corr, b1.x), 0.f);
    o1.y = fmaxf(fmaf(gs, (float)tot[5] - corr, b1.y), 0.f);
    o1.z = fmaxf(fmaf(gs, (float)tot[6] - corr, b1.z), 0.f);
    o1.w = fmaxf(fmaf(gs, (float)tot[7] - corr, b1.w), 0.f);
    *reinterpret_cast<float4*>(op) = o0;
    *reinterpret_cast<float4*>(op + 4) = o1;
  }
}

// =================== fp32 fallback path (ws too small) ====================
__global__ __launch_bounds__(256) void boundaries_kernel(
    const int* __restrict__ segs, int* __restrict__ seg_start, int T, int B) {
  const int i = blockIdx.x * 256 + threadIdx.x;
  if (i > T) return;
  const int cur = (i < T) ? segs[i] : B;
  const int prev = (i > 0) ? segs[i - 1] : -1;
  for (int s = prev + 1; s <= cur; ++s) seg_start[s] = i;
}

#define LOADF(u, TIDX)                                                     \
  const int t##u = tokens[(TIDX)];                                         \
  const float4 e##u = *reinterpret_cast<const float4*>(                    \
      emb + (size_t)t##u * DIM + c4);
#define ADDF(u) { acc.x += e##u.x; acc.y += e##u.y; acc.z += e##u.z; acc.w += e##u.w; }

__global__ __launch_bounds__(256, 4) void segsum_f32(
    const int* __restrict__ tokens, const float* __restrict__ emb,
    const int* __restrict__ seg_start, float* __restrict__ bow, int B) {
  const int seg = blockIdx.x * 4 + (threadIdx.x >> 6);
  if (seg >= B) return;
  const int lane = threadIdx.x & 63;
  const int half = lane >> 5;
  const int c4 = (lane & 31) * 4;
  const int lo = seg_start[seg], hi = seg_start[seg + 1];
  const int cnt = hi - lo;
  float4 acc = make_float4(0.f, 0.f, 0.f, 0.f);

  int base = lo;
  const int nb = cnt >> 4;
  for (int b = 0; b < nb; ++b, base += 16) {
    LOADF(0, base + 0 + half)  LOADF(1, base + 2 + half)
    LOADF(2, base + 4 + half)  LOADF(3, base + 6 + half)
    LOADF(4, base + 8 + half)  LOADF(5, base + 10 + half)
    LOADF(6, base + 12 + half) LOADF(7, base + 14 + half)
    ADDF(0) ADDF(1) ADDF(2) ADDF(3) ADDF(4) ADDF(5) ADDF(6) ADDF(7)
  }
  if (cnt & 15) {
    const int last = hi - 1;
#define LOADT(u) const int i##u = base + 2 * u + half; LOADF(u, min(i##u, last))
    LOADT(0) LOADT(1) LOADT(2) LOADT(3)
    LOADT(4) LOADT(5) LOADT(6) LOADT(7)
    if (i0 <= last) ADDF(0)
    if (i1 <= last) ADDF(1)
    if (i2 <= last) ADDF(2)
    if (i3 <= last) ADDF(3)
    if (i4 <= last) ADDF(4)
    if (i5 <= last) ADDF(5)
    if (i6 <= last) ADDF(6)
    if (i7 <= last) ADDF(7)
#undef LOADT
  }
  acc.x += __shfl_xor(acc.x, 32);
  acc.y += __shfl_xor(acc.y, 32);
  acc.z += __shfl_xor(acc.z, 32);
  acc.w += __shfl_xor(acc.w, 32);
  if (half == 0)
    *reinterpret_cast<float4*>(bow + (size_t)seg * DIM + c4) = acc;
}

// out = relu(bow @ W + b), in-place over d_out (fallback only)
__global__ __launch_bounds__(256) void gemm_bias_relu(
    const float* __restrict__ bow, const float* __restrict__ W,
    const float* __restrict__ bias, float* __restrict__ out) {
  __shared__ float bt[GROWS][DIM];
  const int tid = threadIdx.x;
  const size_t row0 = (size_t)blockIdx.x * GROWS;

  {
    const float4* src = reinterpret_cast<const float4*>(bow + row0 * DIM);
    float4* dst = reinterpret_cast<float4*>(&bt[0][0]);
#pragma unroll
    for (int i = 0; i < (GROWS * DIM / 4) / 256; ++i)
      dst[tid + 256 * i] = src[tid + 256 * i];
  }
  __syncthreads();

  const int cg = tid & 31;
  const int rg = tid >> 5;
  const int c0 = cg * 4;

  float acc[4][4] = {};
#pragma unroll 4
  for (int k = 0; k < DIM; ++k) {
    const float4 w4 = *reinterpret_cast<const float4*>(W + (size_t)k * DIM + c0);
#pragma unroll
    for (int j = 0; j < 4; ++j) {
      const float s = bt[rg * 4 + j][k];
      acc[j][0] = fmaf(s, w4.x, acc[j][0]);
      acc[j][1] = fmaf(s, w4.y, acc[j][1]);
      acc[j][2] = fmaf(s, w4.z, acc[j][2]);
      acc[j][3] = fmaf(s, w4.w, acc[j][3]);
    }
  }

  const float4 bv = *reinterpret_cast<const float4*>(bias + c0);
#pragma unroll
  for (int j = 0; j < 4; ++j) {
    float4 o;
    o.x = fmaxf(acc[j][0] + bv.x, 0.f);
    o.y = fmaxf(acc[j][1] + bv.y, 0.f);
    o.z = fmaxf(acc[j][2] + bv.z, 0.f);
    o.w = fmaxf(acc[j][3] + bv.w, 0.f);
    *reinterpret_cast<float4*>(out + (row0 + rg * 4 + j) * DIM + c0) = o;
  }
}

extern "C" void kernel_launch(void* const* d_in, const int* in_sizes, int n_in,
                              void* d_out, int out_size, void* d_ws, size_t ws_size,
                              hipStream_t stream) {
  const int* tokens = (const int*)d_in[0];
  const int* segs = (const int*)d_in[1];
  const float* emb = (const float*)d_in[2];
  const float* W = (const float*)d_in[3];
  const float* bias = (const float*)d_in[4];
  float* out = (float*)d_out;

  const int T = in_sizes[0];
  const int B = out_size / DIM;       // 16384
  const int V = in_sizes[2] / DIM;    // 100000

  int* seg_start = (int*)d_ws;                       // (B+1) ints
  const size_t ss_bytes = ((size_t)(B + 1) * 4 + 255) & ~(size_t)255;
  const size_t gm_bytes = 256;                       // gmax slot
  const size_t sc_bytes = ((size_t)V * 4 + 255) & ~(size_t)255;

  const bool qok = ws_size >= ss_bytes + gm_bytes + sc_bytes + (size_t)V * DIM;
  if (qok) {
    unsigned* gbits = (unsigned*)((char*)d_ws + ss_bytes);
    float* scales = (float*)((char*)d_ws + ss_bytes + gm_bytes);
    signed char* qtab =
        (signed char*)((char*)d_ws + ss_bytes + gm_bytes + sc_bytes);
    hipMemsetAsync(gbits, 0, 4, stream);
    const int nbBound = (T + 1 + 255) / 256;
    const int NTRANS = 512;                          // transform blocks
    const int mtiles = V / 16;
    prep_kernel<<<NTRANS + nbBound, 256, 0, stream>>>(
        segs, seg_start, emb, W, qtab, scales, gbits, T, B, V, mtiles, NTRANS);
    const int n4 = V * DIM / 4;
    requant_kernel<<<8192, 256, 0, stream>>>(qtab, scales, gbits, n4);
    segsum_u8<<<(B + 3) / 4, 256, 0, stream>>>(
        tokens, (const unsigned char*)qtab, seg_start, gbits, bias, out, B);
  } else {
    float* bow = out;                                // in-place: gather -> GEMM
    boundaries_kernel<<<(T + 1 + 255) / 256, 256, 0, stream>>>(segs, seg_start, T, B);
    segsum_f32<<<(B + 3) / 4, 256, 0, stream>>>(tokens, emb, seg_start, bow, B);
    gemm_bias_relu<<<B / GROWS, 256, 0, stream>>>(bow, W, bias, out);
  }
}

// Round 5
// 57.956 us; speedup vs baseline: 1.2916x; 1.2916x over previous
//
#include <hip/hip_runtime.h>
#include <hip/hip_fp16.h>

#define DIM 128
#define GROWS 32

typedef _Float16 f16x8 __attribute__((ext_vector_type(8)));
typedef float f32x4 __attribute__((ext_vector_type(4)));

// ---------- Kernel 1 (fused): qtab = int8_rowquant(emb @ W), scales[r] =
// rowmax/127, via fp16 MFMA + segment-boundary scan in the same launch.
//
// Round-5 fix: W's B-fragments are staged through LDS. Each block loads W
// once with coalesced float4 reads (L2-hot), converts to fp16, and writes a
// fragment-linear LDS image wlds[n][s][lane][8]; each wave then reads its
// 32 fragments with contiguous ds_read_b128. This replaces the previous
// per-wave 256x stride-512B scalar preload that left prep latency-bound
// (rocprof r4: 44-47us, 876 GB/s, 8% VALUBusy, 16% occupancy).
//
// MFMA fragment layouts (mfma_f32_16x16x32_f16, harness-verified round 1):
//   A (16x32): row = lane&15, k = (lane>>4)*8 + i  -> 8 contiguous floats
//   B (32x16): col = lane&15, k = (lane>>4)*8 + i  -> wlds fragment
//   D (16x16): col = lane&15, row = (lane>>4)*4 + reg
__global__ __launch_bounds__(256, 2) void prep_kernel(
    const int* __restrict__ segs, int* __restrict__ seg_start,
    const float* __restrict__ emb, const float* __restrict__ W,
    signed char* __restrict__ qtab, float* __restrict__ scales,
    int T, int B, int V, int mtiles, int nTrans) {
  if ((int)blockIdx.x >= nTrans) {
    // ---- boundaries: seg_start[s] = lower_bound(segs, s), streaming ----
    const int i = (blockIdx.x - nTrans) * 256 + threadIdx.x;
    if (i > T) return;
    const int cur = (i < T) ? segs[i] : B;
    const int prev = (i > 0) ? segs[i - 1] : -1;
    for (int s = prev + 1; s <= cur; ++s) seg_start[s] = i;
    return;
  }

  // ---- stage W -> fp16 fragment-linear LDS image (32 KB) ----
  // wlds[n][s][lane][i] = fp16(W[s*32 + (lane>>4)*8 + i][n*16 + (lane&15)])
  __shared__ _Float16 wlds[8][4][64][8];
  const int tid = threadIdx.x;
#pragma unroll
  for (int q = 0; q < 16; ++q) {
    const int idx4 = tid + 256 * q;          // 0..4095 float4s of W
    const float4 v = reinterpret_cast<const float4*>(W)[idx4];
    const int r = idx4 >> 5;                 // row 0..127
    const int cb = (idx4 & 31) * 4;          // col 0,4,..,124
    const int s = r >> 5, lg = (r >> 3) & 3, i = r & 7;
    const float vv[4] = {v.x, v.y, v.z, v.w};
#pragma unroll
    for (int k = 0; k < 4; ++k) {
      const int c = cb + k;
      wlds[c >> 4][s][lg * 16 + (c & 15)][i] = (_Float16)vv[k];
    }
  }
  __syncthreads();

  const int wid = blockIdx.x * 4 + (threadIdx.x >> 6);
  const int nwaves = nTrans * 4;
  const int lane = threadIdx.x & 63;
  const int lr = lane & 15;   // A-row / B-col / D-col
  const int lg = lane >> 4;   // k-group (A/B), row-group (D)

  // Per-wave fragment fetch: 32 contiguous 16B LDS reads.
  f16x8 bfrag[8][4];
#pragma unroll
  for (int n = 0; n < 8; ++n)
#pragma unroll
    for (int s = 0; s < 4; ++s)
      bfrag[n][s] = *reinterpret_cast<const f16x8*>(&wlds[n][s][lane][0]);

  for (int mt = wid; mt < mtiles; mt += nwaves) {
    const float* arow = emb + (size_t)(mt * 16 + lr) * DIM;
    f16x8 afrag[4];
#pragma unroll
    for (int s = 0; s < 4; ++s) {
      const float4 a0 = *reinterpret_cast<const float4*>(arow + s * 32 + lg * 8);
      const float4 a1 = *reinterpret_cast<const float4*>(arow + s * 32 + lg * 8 + 4);
      f16x8 f;
      f[0] = (_Float16)a0.x; f[1] = (_Float16)a0.y;
      f[2] = (_Float16)a0.z; f[3] = (_Float16)a0.w;
      f[4] = (_Float16)a1.x; f[5] = (_Float16)a1.y;
      f[6] = (_Float16)a1.z; f[7] = (_Float16)a1.w;
      afrag[s] = f;
    }
    f32x4 accs[8];
#pragma unroll
    for (int n = 0; n < 8; ++n) {
      f32x4 a = {0.f, 0.f, 0.f, 0.f};
#pragma unroll
      for (int s = 0; s < 4; ++s)
        a = __builtin_amdgcn_mfma_f32_16x16x32_f16(afrag[s], bfrag[n][s],
                                                   a, 0, 0, 0);
      accs[n] = a;
    }
    // per-row absmax: in-lane over n, then across the 16 lr lanes
    const int r0 = mt * 16 + lg * 4;
    float inv[4];
#pragma unroll
    for (int j = 0; j < 4; ++j) {
      float mm = fabsf(accs[0][j]);
#pragma unroll
      for (int n = 1; n < 8; ++n) mm = fmaxf(mm, fabsf(accs[n][j]));
      mm = fmaxf(mm, __shfl_xor(mm, 1));
      mm = fmaxf(mm, __shfl_xor(mm, 2));
      mm = fmaxf(mm, __shfl_xor(mm, 4));
      mm = fmaxf(mm, __shfl_xor(mm, 8));
      inv[j] = (mm > 0.f) ? 127.f / mm : 0.f;
      if (lr == 0) scales[r0 + j] = mm * (1.f / 127.f);
    }
#pragma unroll
    for (int n = 0; n < 8; ++n)
#pragma unroll
      for (int j = 0; j < 4; ++j)
        qtab[(size_t)(r0 + j) * DIM + n * 16 + lr] =
            (signed char)(int)rintf(accs[n][j] * inv[j]);
  }

  // tail rows if V % 16 != 0 (dead for V=100000, kept for safety)
  const int tailStart = mtiles * 16;
  if (wid == 0 && tailStart < V) {
    const int c2 = lane * 2;
    for (int r = tailStart; r < V; ++r) {
      float s0 = 0.f, s1 = 0.f;
      for (int k = 0; k < DIM; ++k) {
        const float e = emb[(size_t)r * DIM + k];
        s0 = fmaf(e, W[(size_t)k * DIM + c2], s0);
        s1 = fmaf(e, W[(size_t)k * DIM + c2 + 1], s1);
      }
      float mm = fmaxf(fabsf(s0), fabsf(s1));
      mm = fmaxf(mm, __shfl_xor(mm, 1));
      mm = fmaxf(mm, __shfl_xor(mm, 2));
      mm = fmaxf(mm, __shfl_xor(mm, 4));
      mm = fmaxf(mm, __shfl_xor(mm, 8));
      mm = fmaxf(mm, __shfl_xor(mm, 16));
      mm = fmaxf(mm, __shfl_xor(mm, 32));
      const float iv = (mm > 0.f) ? 127.f / mm : 0.f;
      if (lane == 0) scales[r] = mm * (1.f / 127.f);
      qtab[(size_t)r * DIM + c2] = (signed char)(int)rintf(s0 * iv);
      qtab[(size_t)r * DIM + c2 + 1] = (signed char)(int)rintf(s1 * iv);
    }
  }
}

// ---------- Kernel 2: int8 gather + segment sum + bias + relu -------------
// (r2-verbatim: best measured variant.) One wave per segment. 32-row
// batches: 8 uint2 loads in flight, each load = 4 rows (16 lanes x 8B =
// one 128B row). Per-row fp32 scale folded into the 8 fma-accumulates.
// Cross-group reduce via shfl_xor(16|32); lanes 0-15 apply bias+relu and
// write the 512B output row.

#define ACCB(W_, SH, AI, SV) \
  acc[AI] = fmaf(SV, (float)((int)((W_) << (SH)) >> 24), acc[AI]);
#define ADDQ(u, SV) {                                                      \
  ACCB(r##u.x, 24, 0, SV) ACCB(r##u.x, 16, 1, SV)                          \
  ACCB(r##u.x,  8, 2, SV) ACCB(r##u.x,  0, 3, SV)                          \
  ACCB(r##u.y, 24, 4, SV) ACCB(r##u.y, 16, 5, SV)                          \
  ACCB(r##u.y,  8, 6, SV) ACCB(r##u.y,  0, 7, SV) }
#define LOADQ(u, TIDX)                                                     \
  const int t##u = tokens[(TIDX)];                                         \
  const float s##u = scales[t##u];                                         \
  const uint2 r##u = *reinterpret_cast<const uint2*>(                      \
      qtab + (size_t)t##u * DIM + c8);

__global__ __launch_bounds__(256, 6) void segsum_q8(
    const int* __restrict__ tokens, const signed char* __restrict__ qtab,
    const float* __restrict__ scales, const int* __restrict__ seg_start,
    const float* __restrict__ bias, float* __restrict__ out, int B) {
  const int seg = blockIdx.x * 4 + (threadIdx.x >> 6);
  if (seg >= B) return;
  const int lane = threadIdx.x & 63;
  const int g = lane >> 4;
  const int c8 = (lane & 15) * 8;
  const int lo = seg_start[seg], hi = seg_start[seg + 1];
  const int cnt = hi - lo;
  float acc[8] = {0.f, 0.f, 0.f, 0.f, 0.f, 0.f, 0.f, 0.f};

  int base = lo;
  const int nb = cnt >> 5;
  for (int b = 0; b < nb; ++b, base += 32) {
    LOADQ(0, base + 0 + g)  LOADQ(1, base + 4 + g)
    LOADQ(2, base + 8 + g)  LOADQ(3, base + 12 + g)
    LOADQ(4, base + 16 + g) LOADQ(5, base + 20 + g)
    LOADQ(6, base + 24 + g) LOADQ(7, base + 28 + g)
    ADDQ(0, s0) ADDQ(1, s1) ADDQ(2, s2) ADDQ(3, s3)
    ADDQ(4, s4) ADDQ(5, s5) ADDQ(6, s6) ADDQ(7, s7)
  }
  if (cnt & 31) {
    const int last = hi - 1;
#define LQT(u)                                                             \
  const int i##u = base + 4 * u + g;                                       \
  const int t##u = tokens[min(i##u, last)];                                \
  const float s##u = (i##u <= last) ? scales[t##u] : 0.f;                  \
  const uint2 r##u = *reinterpret_cast<const uint2*>(                      \
      qtab + (size_t)t##u * DIM + c8);
    LQT(0) LQT(1) LQT(2) LQT(3) LQT(4) LQT(5) LQT(6) LQT(7)
    ADDQ(0, s0) ADDQ(1, s1) ADDQ(2, s2) ADDQ(3, s3)
    ADDQ(4, s4) ADDQ(5, s5) ADDQ(6, s6) ADDQ(7, s7)
#undef LQT
  }
#pragma unroll
  for (int i = 0; i < 8; ++i) {
    acc[i] += __shfl_xor(acc[i], 16);
    acc[i] += __shfl_xor(acc[i], 32);
  }
  if (g == 0) {
    const float4 b0 = *reinterpret_cast<const float4*>(bias + c8);
    const float4 b1 = *reinterpret_cast<const float4*>(bias + c8 + 4);
    float4 o0, o1;
    o0.x = fmaxf(acc[0] + b0.x, 0.f);
    o0.y = fmaxf(acc[1] + b0.y, 0.f);
    o0.z = fmaxf(acc[2] + b0.z, 0.f);
    o0.w = fmaxf(acc[3] + b0.w, 0.f);
    o1.x = fmaxf(acc[4] + b1.x, 0.f);
    o1.y = fmaxf(acc[5] + b1.y, 0.f);
    o1.z = fmaxf(acc[6] + b1.z, 0.f);
    o1.w = fmaxf(acc[7] + b1.w, 0.f);
    *reinterpret_cast<float4*>(out + (size_t)seg * DIM + c8) = o0;
    *reinterpret_cast<float4*>(out + (size_t)seg * DIM + c8 + 4) = o1;
  }
}

// =================== fp32 fallback path (ws too small) ====================
__global__ __launch_bounds__(256) void boundaries_kernel(
    const int* __restrict__ segs, int* __restrict__ seg_start, int T, int B) {
  const int i = blockIdx.x * 256 + threadIdx.x;
  if (i > T) return;
  const int cur = (i < T) ? segs[i] : B;
  const int prev = (i > 0) ? segs[i - 1] : -1;
  for (int s = prev + 1; s <= cur; ++s) seg_start[s] = i;
}

#define LOADF(u, TIDX)                                                     \
  const int t##u = tokens[(TIDX)];                                         \
  const float4 e##u = *reinterpret_cast<const float4*>(                    \
      emb + (size_t)t##u * DIM + c4);
#define ADDF(u) { acc.x += e##u.x; acc.y += e##u.y; acc.z += e##u.z; acc.w += e##u.w; }

__global__ __launch_bounds__(256, 4) void segsum_f32(
    const int* __restrict__ tokens, const float* __restrict__ emb,
    const int* __restrict__ seg_start, float* __restrict__ bow, int B) {
  const int seg = blockIdx.x * 4 + (threadIdx.x >> 6);
  if (seg >= B) return;
  const int lane = threadIdx.x & 63;
  const int half = lane >> 5;
  const int c4 = (lane & 31) * 4;
  const int lo = seg_start[seg], hi = seg_start[seg + 1];
  const int cnt = hi - lo;
  float4 acc = make_float4(0.f, 0.f, 0.f, 0.f);

  int base = lo;
  const int nb = cnt >> 4;
  for (int b = 0; b < nb; ++b, base += 16) {
    LOADF(0, base + 0 + half)  LOADF(1, base + 2 + half)
    LOADF(2, base + 4 + half)  LOADF(3, base + 6 + half)
    LOADF(4, base + 8 + half)  LOADF(5, base + 10 + half)
    LOADF(6, base + 12 + half) LOADF(7, base + 14 + half)
    ADDF(0) ADDF(1) ADDF(2) ADDF(3) ADDF(4) ADDF(5) ADDF(6) ADDF(7)
  }
  if (cnt & 15) {
    const int last = hi - 1;
#define LOADT(u) const int i##u = base + 2 * u + half; LOADF(u, min(i##u, last))
    LOADT(0) LOADT(1) LOADT(2) LOADT(3)
    LOADT(4) LOADT(5) LOADT(6) LOADT(7)
    if (i0 <= last) ADDF(0)
    if (i1 <= last) ADDF(1)
    if (i2 <= last) ADDF(2)
    if (i3 <= last) ADDF(3)
    if (i4 <= last) ADDF(4)
    if (i5 <= last) ADDF(5)
    if (i6 <= last) ADDF(6)
    if (i7 <= last) ADDF(7)
#undef LOADT
  }
  acc.x += __shfl_xor(acc.x, 32);
  acc.y += __shfl_xor(acc.y, 32);
  acc.z += __shfl_xor(acc.z, 32);
  acc.w += __shfl_xor(acc.w, 32);
  if (half == 0)
    *reinterpret_cast<float4*>(bow + (size_t)seg * DIM + c4) = acc;
}

// out = relu(bow @ W + b), in-place over d_out (fallback only)
__global__ __launch_bounds__(256) void gemm_bias_relu(
    const float* __restrict__ bow, const float* __restrict__ W,
    const float* __restrict__ bias, float* __restrict__ out) {
  __shared__ float bt[GROWS][DIM];
  const int tid = threadIdx.x;
  const size_t row0 = (size_t)blockIdx.x * GROWS;

  {
    const float4* src = reinterpret_cast<const float4*>(bow + row0 * DIM);
    float4* dst = reinterpret_cast<float4*>(&bt[0][0]);
#pragma unroll
    for (int i = 0; i < (GROWS * DIM / 4) / 256; ++i)
      dst[tid + 256 * i] = src[tid + 256 * i];
  }
  __syncthreads();

  const int cg = tid & 31;
  const int rg = tid >> 5;
  const int c0 = cg * 4;

  float acc[4][4] = {};
#pragma unroll 4
  for (int k = 0; k < DIM; ++k) {
    const float4 w4 = *reinterpret_cast<const float4*>(W + (size_t)k * DIM + c0);
#pragma unroll
    for (int j = 0; j < 4; ++j) {
      const float s = bt[rg * 4 + j][k];
      acc[j][0] = fmaf(s, w4.x, acc[j][0]);
      acc[j][1] = fmaf(s, w4.y, acc[j][1]);
      acc[j][2] = fmaf(s, w4.z, acc[j][2]);
      acc[j][3] = fmaf(s, w4.w, acc[j][3]);
    }
  }

  const float4 bv = *reinterpret_cast<const float4*>(bias + c0);
#pragma unroll
  for (int j = 0; j < 4; ++j) {
    float4 o;
    o.x = fmaxf(acc[j][0] + bv.x, 0.f);
    o.y = fmaxf(acc[j][1] + bv.y, 0.f);
    o.z = fmaxf(acc[j][2] + bv.z, 0.f);
    o.w = fmaxf(acc[j][3] + bv.w, 0.f);
    *reinterpret_cast<float4*>(out + (row0 + rg * 4 + j) * DIM + c0) = o;
  }
}

extern "C" void kernel_launch(void* const* d_in, const int* in_sizes, int n_in,
                              void* d_out, int out_size, void* d_ws, size_t ws_size,
                              hipStream_t stream) {
  const int* tokens = (const int*)d_in[0];
  const int* segs = (const int*)d_in[1];
  const float* emb = (const float*)d_in[2];
  const float* W = (const float*)d_in[3];
  const float* bias = (const float*)d_in[4];
  float* out = (float*)d_out;

  const int T = in_sizes[0];
  const int B = out_size / DIM;       // 16384
  const int V = in_sizes[2] / DIM;    // 100000

  int* seg_start = (int*)d_ws;                       // (B+1) ints
  const size_t ss_bytes = ((size_t)(B + 1) * 4 + 255) & ~(size_t)255;
  const size_t sc_bytes = ((size_t)V * 4 + 255) & ~(size_t)255;

  const bool qok = ws_size >= ss_bytes + sc_bytes + (size_t)V * DIM;
  if (qok) {
    float* scales = (float*)((char*)d_ws + ss_bytes);
    signed char* qtab = (signed char*)((char*)d_ws + ss_bytes + sc_bytes);
    const int nbBound = (T + 1 + 255) / 256;
    const int NTRANS = 782;                          // transform blocks
    const int mtiles = V / 16;
    prep_kernel<<<NTRANS + nbBound, 256, 0, stream>>>(
        segs, seg_start, emb, W, qtab, scales, T, B, V, mtiles, NTRANS);
    segsum_q8<<<(B + 3) / 4, 256, 0, stream>>>(
        tokens, qtab, scales, seg_start, bias, out, B);
  } else {
    float* bow = out;                                // in-place: gather -> GEMM
    boundaries_kernel<<<(T + 1 + 255) / 256, 256, 0, stream>>>(segs, seg_start, T, B);
    segsum_f32<<<(B + 3) / 4, 256, 0, stream>>>(tokens, emb, seg_start, bow, B);
    gemm_bias_relu<<<B / GROWS, 256, 0, stream>>>(bow, W, bias, out);
  }
}

// Round 6
// 53.280 us; speedup vs baseline: 1.4050x; 1.0878x over previous
//
#include <hip/hip_runtime.h>
#include <hip/hip_fp16.h>

#define DIM 128
#define GROWS 32

typedef _Float16 f16x8 __attribute__((ext_vector_type(8)));
typedef float f32x4 __attribute__((ext_vector_type(4)));

// ---------- Kernel 1 (fused): qtab = int8_rowquant(emb @ W), scales[r] =
// rowmax/127, via fp16 MFMA + segment-boundary scan in the same launch.
// r2-exact register-preload version (proven ~14us). NO single-address
// atomics (r4 lesson: ~12K same-address atomicMax = +30us queue drain),
// NO LDS staging / extra block generations (r5 lesson: +10us).
//
// MFMA fragment layouts (mfma_f32_16x16x32_f16, harness-verified round 1):
//   A (16x32): row = lane&15, k = (lane>>4)*8 + i  -> 8 contiguous floats
//   B (32x16): col = lane&15, k = (lane>>4)*8 + i  -> stride-DIM scalars
//   D (16x16): col = lane&15, row = (lane>>4)*4 + reg
__global__ __launch_bounds__(256, 2) void prep_kernel(
    const int* __restrict__ segs, int* __restrict__ seg_start,
    const float* __restrict__ emb, const float* __restrict__ W,
    signed char* __restrict__ qtab, float* __restrict__ scales,
    int T, int B, int V, int mtiles, int nTrans) {
  if ((int)blockIdx.x >= nTrans) {
    // ---- boundaries: seg_start[s] = lower_bound(segs, s), streaming ----
    const int i = (blockIdx.x - nTrans) * 256 + threadIdx.x;
    if (i > T) return;
    const int cur = (i < T) ? segs[i] : B;
    const int prev = (i > 0) ? segs[i - 1] : -1;
    for (int s = prev + 1; s <= cur; ++s) seg_start[s] = i;
    return;
  }

  const int wid = blockIdx.x * 4 + (threadIdx.x >> 6);
  const int nwaves = nTrans * 4;
  const int lane = threadIdx.x & 63;
  const int lr = lane & 15;   // A-row / B-col / D-col
  const int lg = lane >> 4;   // k-group (A/B), row-group (D)

  // Preload all B fragments of W (fp32 -> fp16). W is 64KB, L1/L2-hot.
  f16x8 bfrag[8][4];
#pragma unroll
  for (int n = 0; n < 8; ++n)
#pragma unroll
    for (int s = 0; s < 4; ++s) {
      const float* wp = W + (size_t)(s * 32 + lg * 8) * DIM + n * 16 + lr;
      f16x8 f;
#pragma unroll
      for (int i = 0; i < 8; ++i) f[i] = (_Float16)wp[(size_t)i * DIM];
      bfrag[n][s] = f;
    }

  for (int mt = wid; mt < mtiles; mt += nwaves) {
    const float* arow = emb + (size_t)(mt * 16 + lr) * DIM;
    f16x8 afrag[4];
#pragma unroll
    for (int s = 0; s < 4; ++s) {
      const float4 a0 = *reinterpret_cast<const float4*>(arow + s * 32 + lg * 8);
      const float4 a1 = *reinterpret_cast<const float4*>(arow + s * 32 + lg * 8 + 4);
      f16x8 f;
      f[0] = (_Float16)a0.x; f[1] = (_Float16)a0.y;
      f[2] = (_Float16)a0.z; f[3] = (_Float16)a0.w;
      f[4] = (_Float16)a1.x; f[5] = (_Float16)a1.y;
      f[6] = (_Float16)a1.z; f[7] = (_Float16)a1.w;
      afrag[s] = f;
    }
    f32x4 accs[8];
#pragma unroll
    for (int n = 0; n < 8; ++n) {
      f32x4 a = {0.f, 0.f, 0.f, 0.f};
#pragma unroll
      for (int s = 0; s < 4; ++s)
        a = __builtin_amdgcn_mfma_f32_16x16x32_f16(afrag[s], bfrag[n][s],
                                                   a, 0, 0, 0);
      accs[n] = a;
    }
    // per-row absmax: in-lane over n, then across the 16 lr lanes
    const int r0 = mt * 16 + lg * 4;
    float inv[4];
#pragma unroll
    for (int j = 0; j < 4; ++j) {
      float mm = fabsf(accs[0][j]);
#pragma unroll
      for (int n = 1; n < 8; ++n) mm = fmaxf(mm, fabsf(accs[n][j]));
      mm = fmaxf(mm, __shfl_xor(mm, 1));
      mm = fmaxf(mm, __shfl_xor(mm, 2));
      mm = fmaxf(mm, __shfl_xor(mm, 4));
      mm = fmaxf(mm, __shfl_xor(mm, 8));
      inv[j] = (mm > 0.f) ? 127.f / mm : 0.f;
      if (lr == 0) scales[r0 + j] = mm * (1.f / 127.f);
    }
#pragma unroll
    for (int n = 0; n < 8; ++n)
#pragma unroll
      for (int j = 0; j < 4; ++j)
        qtab[(size_t)(r0 + j) * DIM + n * 16 + lr] =
            (signed char)(int)rintf(accs[n][j] * inv[j]);
  }

  // tail rows if V % 16 != 0 (dead for V=100000, kept for safety)
  const int tailStart = mtiles * 16;
  if (wid == 0 && tailStart < V) {
    const int c2 = lane * 2;
    for (int r = tailStart; r < V; ++r) {
      float s0 = 0.f, s1 = 0.f;
      for (int k = 0; k < DIM; ++k) {
        const float e = emb[(size_t)r * DIM + k];
        s0 = fmaf(e, W[(size_t)k * DIM + c2], s0);
        s1 = fmaf(e, W[(size_t)k * DIM + c2 + 1], s1);
      }
      float mm = fmaxf(fabsf(s0), fabsf(s1));
      mm = fmaxf(mm, __shfl_xor(mm, 1));
      mm = fmaxf(mm, __shfl_xor(mm, 2));
      mm = fmaxf(mm, __shfl_xor(mm, 4));
      mm = fmaxf(mm, __shfl_xor(mm, 8));
      mm = fmaxf(mm, __shfl_xor(mm, 16));
      mm = fmaxf(mm, __shfl_xor(mm, 32));
      const float iv = (mm > 0.f) ? 127.f / mm : 0.f;
      if (lane == 0) scales[r] = mm * (1.f / 127.f);
      qtab[(size_t)r * DIM + c2] = (signed char)(int)rintf(s0 * iv);
      qtab[(size_t)r * DIM + c2 + 1] = (signed char)(int)rintf(s1 * iv);
    }
  }
}

// ---------- Kernel 1c: token-aligned scale array ---------------------------
// st[i] = scales[tokens[i]]. Runs alone between prep and segsum: working
// set = 400KB scales (fully L2-resident, no qtab churn) + streamed
// tokens/st. Turns segsum's 819K random 64B scale-line fills into a
// coalesced 3.3MB stream.
__global__ __launch_bounds__(256) void st_kernel(
    const int* __restrict__ tokens, const float* __restrict__ scales,
    float* __restrict__ st, int T) {
  int i = blockIdx.x * 256 + threadIdx.x;
  const int stride = gridDim.x * 256;
  for (; i < T; i += stride) st[i] = scales[tokens[i]];
}

// ---------- Kernel 2: int8 gather + segment sum + bias + relu -------------
// r2-proven geometry. One wave per segment. 32-row batches: 8 uint2 loads
// in flight, each load = 4 rows (16 lanes x 8B = one 128B row). Per-row
// scale now comes from the STREAMED token-aligned st[] (sequential,
// L1/L2-hot) instead of a random scales[token] gather. Cross-group reduce
// via shfl_xor(16|32); lanes 0-15 apply bias+relu, write the 512B row.

#define ACCB(W_, SH, AI, SV) \
  acc[AI] = fmaf(SV, (float)((int)((W_) << (SH)) >> 24), acc[AI]);
#define ADDQ(u, SV) {                                                      \
  ACCB(r##u.x, 24, 0, SV) ACCB(r##u.x, 16, 1, SV)                          \
  ACCB(r##u.x,  8, 2, SV) ACCB(r##u.x,  0, 3, SV)                          \
  ACCB(r##u.y, 24, 4, SV) ACCB(r##u.y, 16, 5, SV)                          \
  ACCB(r##u.y,  8, 6, SV) ACCB(r##u.y,  0, 7, SV) }
#define LOADQ(u, TIDX)                                                     \
  const int t##u = tokens[(TIDX)];                                         \
  const float s##u = st[(TIDX)];                                           \
  const uint2 r##u = *reinterpret_cast<const uint2*>(                      \
      qtab + (size_t)t##u * DIM + c8);

__global__ __launch_bounds__(256, 8) void segsum_q8(
    const int* __restrict__ tokens, const signed char* __restrict__ qtab,
    const float* __restrict__ st, const int* __restrict__ seg_start,
    const float* __restrict__ bias, float* __restrict__ out, int B) {
  const int seg = blockIdx.x * 4 + (threadIdx.x >> 6);
  if (seg >= B) return;
  const int lane = threadIdx.x & 63;
  const int g = lane >> 4;
  const int c8 = (lane & 15) * 8;
  const int lo = seg_start[seg], hi = seg_start[seg + 1];
  const int cnt = hi - lo;
  float acc[8] = {0.f, 0.f, 0.f, 0.f, 0.f, 0.f, 0.f, 0.f};

  int base = lo;
  const int nb = cnt >> 5;
  for (int b = 0; b < nb; ++b, base += 32) {
    LOADQ(0, base + 0 + g)  LOADQ(1, base + 4 + g)
    LOADQ(2, base + 8 + g)  LOADQ(3, base + 12 + g)
    LOADQ(4, base + 16 + g) LOADQ(5, base + 20 + g)
    LOADQ(6, base + 24 + g) LOADQ(7, base + 28 + g)
    ADDQ(0, s0) ADDQ(1, s1) ADDQ(2, s2) ADDQ(3, s3)
    ADDQ(4, s4) ADDQ(5, s5) ADDQ(6, s6) ADDQ(7, s7)
  }
  if (cnt & 31) {
    const int last = hi - 1;
#define LQT(u)                                                             \
  const int i##u = base + 4 * u + g;                                       \
  const int im##u = min(i##u, last);                                       \
  const int t##u = tokens[im##u];                                          \
  const float s##u = (i##u <= last) ? st[im##u] : 0.f;                     \
  const uint2 r##u = *reinterpret_cast<const uint2*>(                      \
      qtab + (size_t)t##u * DIM + c8);
    LQT(0) LQT(1) LQT(2) LQT(3) LQT(4) LQT(5) LQT(6) LQT(7)
    ADDQ(0, s0) ADDQ(1, s1) ADDQ(2, s2) ADDQ(3, s3)
    ADDQ(4, s4) ADDQ(5, s5) ADDQ(6, s6) ADDQ(7, s7)
#undef LQT
  }
#pragma unroll
  for (int i = 0; i < 8; ++i) {
    acc[i] += __shfl_xor(acc[i], 16);
    acc[i] += __shfl_xor(acc[i], 32);
  }
  if (g == 0) {
    const float4 b0 = *reinterpret_cast<const float4*>(bias + c8);
    const float4 b1 = *reinterpret_cast<const float4*>(bias + c8 + 4);
    float4 o0, o1;
    o0.x = fmaxf(acc[0] + b0.x, 0.f);
    o0.y = fmaxf(acc[1] + b0.y, 0.f);
    o0.z = fmaxf(acc[2] + b0.z, 0.f);
    o0.w = fmaxf(acc[3] + b0.w, 0.f);
    o1.x = fmaxf(acc[4] + b1.x, 0.f);
    o1.y = fmaxf(acc[5] + b1.y, 0.f);
    o1.z = fmaxf(acc[6] + b1.z, 0.f);
    o1.w = fmaxf(acc[7] + b1.w, 0.f);
    *reinterpret_cast<float4*>(out + (size_t)seg * DIM + c8) = o0;
    *reinterpret_cast<float4*>(out + (size_t)seg * DIM + c8 + 4) = o1;
  }
}

// =================== fp32 fallback path (ws too small) ====================
__global__ __launch_bounds__(256) void boundaries_kernel(
    const int* __restrict__ segs, int* __restrict__ seg_start, int T, int B) {
  const int i = blockIdx.x * 256 + threadIdx.x;
  if (i > T) return;
  const int cur = (i < T) ? segs[i] : B;
  const int prev = (i > 0) ? segs[i - 1] : -1;
  for (int s = prev + 1; s <= cur; ++s) seg_start[s] = i;
}

#define LOADF(u, TIDX)                                                     \
  const int t##u = tokens[(TIDX)];                                         \
  const float4 e##u = *reinterpret_cast<const float4*>(                    \
      emb + (size_t)t##u * DIM + c4);
#define ADDF(u) { acc.x += e##u.x; acc.y += e##u.y; acc.z += e##u.z; acc.w += e##u.w; }

__global__ __launch_bounds__(256, 4) void segsum_f32(
    const int* __restrict__ tokens, const float* __restrict__ emb,
    const int* __restrict__ seg_start, float* __restrict__ bow, int B) {
  const int seg = blockIdx.x * 4 + (threadIdx.x >> 6);
  if (seg >= B) return;
  const int lane = threadIdx.x & 63;
  const int half = lane >> 5;
  const int c4 = (lane & 31) * 4;
  const int lo = seg_start[seg], hi = seg_start[seg + 1];
  const int cnt = hi - lo;
  float4 acc = make_float4(0.f, 0.f, 0.f, 0.f);

  int base = lo;
  const int nb = cnt >> 4;
  for (int b = 0; b < nb; ++b, base += 16) {
    LOADF(0, base + 0 + half)  LOADF(1, base + 2 + half)
    LOADF(2, base + 4 + half)  LOADF(3, base + 6 + half)
    LOADF(4, base + 8 + half)  LOADF(5, base + 10 + half)
    LOADF(6, base + 12 + half) LOADF(7, base + 14 + half)
    ADDF(0) ADDF(1) ADDF(2) ADDF(3) ADDF(4) ADDF(5) ADDF(6) ADDF(7)
  }
  if (cnt & 15) {
    const int last = hi - 1;
#define LOADT(u) const int i##u = base + 2 * u + half; LOADF(u, min(i##u, last))
    LOADT(0) LOADT(1) LOADT(2) LOADT(3)
    LOADT(4) LOADT(5) LOADT(6) LOADT(7)
    if (i0 <= last) ADDF(0)
    if (i1 <= last) ADDF(1)
    if (i2 <= last) ADDF(2)
    if (i3 <= last) ADDF(3)
    if (i4 <= last) ADDF(4)
    if (i5 <= last) ADDF(5)
    if (i6 <= last) ADDF(6)
    if (i7 <= last) ADDF(7)
#undef LOADT
  }
  acc.x += __shfl_xor(acc.x, 32);
  acc.y += __shfl_xor(acc.y, 32);
  acc.z += __shfl_xor(acc.z, 32);
  acc.w += __shfl_xor(acc.w, 32);
  if (half == 0)
    *reinterpret_cast<float4*>(bow + (size_t)seg * DIM + c4) = acc;
}

// out = relu(bow @ W + b), in-place over d_out (fallback only)
__global__ __launch_bounds__(256) void gemm_bias_relu(
    const float* __restrict__ bow, const float* __restrict__ W,
    const float* __restrict__ bias, float* __restrict__ out) {
  __shared__ float bt[GROWS][DIM];
  const int tid = threadIdx.x;
  const size_t row0 = (size_t)blockIdx.x * GROWS;

  {
    const float4* src = reinterpret_cast<const float4*>(bow + row0 * DIM);
    float4* dst = reinterpret_cast<float4*>(&bt[0][0]);
#pragma unroll
    for (int i = 0; i < (GROWS * DIM / 4) / 256; ++i)
      dst[tid + 256 * i] = src[tid + 256 * i];
  }
  __syncthreads();

  const int cg = tid & 31;
  const int rg = tid >> 5;
  const int c0 = cg * 4;

  float acc[4][4] = {};
#pragma unroll 4
  for (int k = 0; k < DIM; ++k) {
    const float4 w4 = *reinterpret_cast<const float4*>(W + (size_t)k * DIM + c0);
#pragma unroll
    for (int j = 0; j < 4; ++j) {
      const float s = bt[rg * 4 + j][k];
      acc[j][0] = fmaf(s, w4.x, acc[j][0]);
      acc[j][1] = fmaf(s, w4.y, acc[j][1]);
      acc[j][2] = fmaf(s, w4.z, acc[j][2]);
      acc[j][3] = fmaf(s, w4.w, acc[j][3]);
    }
  }

  const float4 bv = *reinterpret_cast<const float4*>(bias + c0);
#pragma unroll
  for (int j = 0; j < 4; ++j) {
    float4 o;
    o.x = fmaxf(acc[j][0] + bv.x, 0.f);
    o.y = fmaxf(acc[j][1] + bv.y, 0.f);
    o.z = fmaxf(acc[j][2] + bv.z, 0.f);
    o.w = fmaxf(acc[j][3] + bv.w, 0.f);
    *reinterpret_cast<float4*>(out + (row0 + rg * 4 + j) * DIM + c0) = o;
  }
}

extern "C" void kernel_launch(void* const* d_in, const int* in_sizes, int n_in,
                              void* d_out, int out_size, void* d_ws, size_t ws_size,
                              hipStream_t stream) {
  const int* tokens = (const int*)d_in[0];
  const int* segs = (const int*)d_in[1];
  const float* emb = (const float*)d_in[2];
  const float* W = (const float*)d_in[3];
  const float* bias = (const float*)d_in[4];
  float* out = (float*)d_out;

  const int T = in_sizes[0];
  const int B = out_size / DIM;       // 16384
  const int V = in_sizes[2] / DIM;    // 100000

  int* seg_start = (int*)d_ws;                       // (B+1) ints
  const size_t ss_bytes = ((size_t)(B + 1) * 4 + 255) & ~(size_t)255;
  const size_t sc_bytes = ((size_t)V * 4 + 255) & ~(size_t)255;
  const size_t st_bytes = ((size_t)T * 4 + 255) & ~(size_t)255;

  const bool qok =
      ws_size >= ss_bytes + sc_bytes + st_bytes + (size_t)V * DIM;
  if (qok) {
    float* scales = (float*)((char*)d_ws + ss_bytes);
    float* st = (float*)((char*)d_ws + ss_bytes + sc_bytes);
    signed char* qtab =
        (signed char*)((char*)d_ws + ss_bytes + sc_bytes + st_bytes);
    const int nbBound = (T + 1 + 255) / 256;
    const int NTRANS = 512;                          // transform blocks
    const int mtiles = V / 16;
    prep_kernel<<<NTRANS + nbBound, 256, 0, stream>>>(
        segs, seg_start, emb, W, qtab, scales, T, B, V, mtiles, NTRANS);
    st_kernel<<<1600, 256, 0, stream>>>(tokens, scales, st, T);
    segsum_q8<<<(B + 3) / 4, 256, 0, stream>>>(
        tokens, qtab, st, seg_start, bias, out, B);
  } else {
    float* bow = out;                                // in-place: gather -> GEMM
    boundaries_kernel<<<(T + 1 + 255) / 256, 256, 0, stream>>>(segs, seg_start, T, B);
    segsum_f32<<<(B + 3) / 4, 256, 0, stream>>>(tokens, emb, seg_start, bow, B);
    gemm_bias_relu<<<B / GROWS, 256, 0, stream>>>(bow, W, bias, out);
  }
}

// Round 7
// 46.756 us; speedup vs baseline: 1.6010x; 1.1395x over previous
//
#include <hip/hip_runtime.h>
#include <hip/hip_fp16.h>

#define DIM 128
#define GROWS 32

typedef _Float16 f16x8 __attribute__((ext_vector_type(8)));
typedef float f32x4 __attribute__((ext_vector_type(4)));

// ---------- Kernel 1 (fused): qtab = int8_rowquant(emb @ W), scales[r] =
// rowmax/127, via fp16 MFMA + segment-boundary scan in the same launch.
// r2-exact register-preload version (proven ~15us). NO single-address
// atomics (r4: +30us queue drain), NO LDS staging (r5: +10us), NO st
// stream (r6: +5us, scales are L2-resident anyway).
//
// MFMA fragment layouts (mfma_f32_16x16x32_f16, harness-verified round 1):
//   A (16x32): row = lane&15, k = (lane>>4)*8 + i  -> 8 contiguous floats
//   B (32x16): col = lane&15, k = (lane>>4)*8 + i  -> stride-DIM scalars
//   D (16x16): col = lane&15, row = (lane>>4)*4 + reg
__global__ __launch_bounds__(256, 2) void prep_kernel(
    const int* __restrict__ segs, int* __restrict__ seg_start,
    const float* __restrict__ emb, const float* __restrict__ W,
    signed char* __restrict__ qtab, float* __restrict__ scales,
    int T, int B, int V, int mtiles, int nTrans) {
  if ((int)blockIdx.x >= nTrans) {
    // ---- boundaries: seg_start[s] = lower_bound(segs, s), streaming ----
    const int i = (blockIdx.x - nTrans) * 256 + threadIdx.x;
    if (i > T) return;
    const int cur = (i < T) ? segs[i] : B;
    const int prev = (i > 0) ? segs[i - 1] : -1;
    for (int s = prev + 1; s <= cur; ++s) seg_start[s] = i;
    return;
  }

  const int wid = blockIdx.x * 4 + (threadIdx.x >> 6);
  const int nwaves = nTrans * 4;
  const int lane = threadIdx.x & 63;
  const int lr = lane & 15;   // A-row / B-col / D-col
  const int lg = lane >> 4;   // k-group (A/B), row-group (D)

  // Preload all B fragments of W (fp32 -> fp16). W is 64KB, L1/L2-hot.
  f16x8 bfrag[8][4];
#pragma unroll
  for (int n = 0; n < 8; ++n)
#pragma unroll
    for (int s = 0; s < 4; ++s) {
      const float* wp = W + (size_t)(s * 32 + lg * 8) * DIM + n * 16 + lr;
      f16x8 f;
#pragma unroll
      for (int i = 0; i < 8; ++i) f[i] = (_Float16)wp[(size_t)i * DIM];
      bfrag[n][s] = f;
    }

  for (int mt = wid; mt < mtiles; mt += nwaves) {
    const float* arow = emb + (size_t)(mt * 16 + lr) * DIM;
    f16x8 afrag[4];
#pragma unroll
    for (int s = 0; s < 4; ++s) {
      const float4 a0 = *reinterpret_cast<const float4*>(arow + s * 32 + lg * 8);
      const float4 a1 = *reinterpret_cast<const float4*>(arow + s * 32 + lg * 8 + 4);
      f16x8 f;
      f[0] = (_Float16)a0.x; f[1] = (_Float16)a0.y;
      f[2] = (_Float16)a0.z; f[3] = (_Float16)a0.w;
      f[4] = (_Float16)a1.x; f[5] = (_Float16)a1.y;
      f[6] = (_Float16)a1.z; f[7] = (_Float16)a1.w;
      afrag[s] = f;
    }
    f32x4 accs[8];
#pragma unroll
    for (int n = 0; n < 8; ++n) {
      f32x4 a = {0.f, 0.f, 0.f, 0.f};
#pragma unroll
      for (int s = 0; s < 4; ++s)
        a = __builtin_amdgcn_mfma_f32_16x16x32_f16(afrag[s], bfrag[n][s],
                                                   a, 0, 0, 0);
      accs[n] = a;
    }
    // per-row absmax: in-lane over n, then across the 16 lr lanes
    const int r0 = mt * 16 + lg * 4;
    float inv[4];
#pragma unroll
    for (int j = 0; j < 4; ++j) {
      float mm = fabsf(accs[0][j]);
#pragma unroll
      for (int n = 1; n < 8; ++n) mm = fmaxf(mm, fabsf(accs[n][j]));
      mm = fmaxf(mm, __shfl_xor(mm, 1));
      mm = fmaxf(mm, __shfl_xor(mm, 2));
      mm = fmaxf(mm, __shfl_xor(mm, 4));
      mm = fmaxf(mm, __shfl_xor(mm, 8));
      inv[j] = (mm > 0.f) ? 127.f / mm : 0.f;
      if (lr == 0) scales[r0 + j] = mm * (1.f / 127.f);
    }
#pragma unroll
    for (int n = 0; n < 8; ++n)
#pragma unroll
      for (int j = 0; j < 4; ++j)
        qtab[(size_t)(r0 + j) * DIM + n * 16 + lr] =
            (signed char)(int)rintf(accs[n][j] * inv[j]);
  }

  // tail rows if V % 16 != 0 (dead for V=100000, kept for safety)
  const int tailStart = mtiles * 16;
  if (wid == 0 && tailStart < V) {
    const int c2 = lane * 2;
    for (int r = tailStart; r < V; ++r) {
      float s0 = 0.f, s1 = 0.f;
      for (int k = 0; k < DIM; ++k) {
        const float e = emb[(size_t)r * DIM + k];
        s0 = fmaf(e, W[(size_t)k * DIM + c2], s0);
        s1 = fmaf(e, W[(size_t)k * DIM + c2 + 1], s1);
      }
      float mm = fmaxf(fabsf(s0), fabsf(s1));
      mm = fmaxf(mm, __shfl_xor(mm, 1));
      mm = fmaxf(mm, __shfl_xor(mm, 2));
      mm = fmaxf(mm, __shfl_xor(mm, 4));
      mm = fmaxf(mm, __shfl_xor(mm, 8));
      mm = fmaxf(mm, __shfl_xor(mm, 16));
      mm = fmaxf(mm, __shfl_xor(mm, 32));
      const float iv = (mm > 0.f) ? 127.f / mm : 0.f;
      if (lane == 0) scales[r] = mm * (1.f / 127.f);
      qtab[(size_t)r * DIM + c2] = (signed char)(int)rintf(s0 * iv);
      qtab[(size_t)r * DIM + c2 + 1] = (signed char)(int)rintf(s1 * iv);
    }
  }
}

// ---------- Kernel 2: int8 gather + segment sum + bias + relu -------------
// One wave per segment (4 waves/block). 64-row clamped batches, deep MLP:
// 8 x dwordx4 loads in flight, each load = 8 rows (8 lanes x 16B = one
// 128B row). Outstanding bytes/wave = 8KB (2x round-2); with (256,4) ->
// 16 waves/CU resident, per-CU in-flight far exceeds BW*latency, so the
// gather should run at the ~5.5TB/s fill rate r1's fp16 gather achieved.
// Phase-split (tokens -> scales+rows -> fma) so dependent chains don't
// serialize; fully unrolled static-index arrays stay in registers.
// r3's failure mode (compiler register starvation at tight bounds ->
// serialized loads, VGPR=40) is avoided with __launch_bounds__(256,4)
// (128-VGPR budget).

#define ACC4(w, o, SV)                                                     \
  acc[(o) + 0] = fmaf(SV, (float)((int)((w) << 24) >> 24), acc[(o) + 0]);  \
  acc[(o) + 1] = fmaf(SV, (float)((int)((w) << 16) >> 24), acc[(o) + 1]);  \
  acc[(o) + 2] = fmaf(SV, (float)((int)((w) <<  8) >> 24), acc[(o) + 2]);  \
  acc[(o) + 3] = fmaf(SV, (float)((int)(w) >> 24),         acc[(o) + 3]);

__global__ __launch_bounds__(256, 4) void segsum_q8(
    const int* __restrict__ tokens, const signed char* __restrict__ qtab,
    const float* __restrict__ scales, const int* __restrict__ seg_start,
    const float* __restrict__ bias, float* __restrict__ out, int B) {
  const int seg = blockIdx.x * 4 + (threadIdx.x >> 6);
  if (seg >= B) return;
  const int lane = threadIdx.x & 63;
  const int g = lane >> 3;            // row-in-octet 0..7
  const int c16 = (lane & 7) * 16;    // byte offset of this lane's 16 dims
  const int lo = seg_start[seg], hi = seg_start[seg + 1];
  const int cnt = hi - lo;
  const int last = hi - 1;
  float acc[16] = {0.f, 0.f, 0.f, 0.f, 0.f, 0.f, 0.f, 0.f,
                   0.f, 0.f, 0.f, 0.f, 0.f, 0.f, 0.f, 0.f};

  const int nbatch = (cnt + 63) >> 6;
  for (int b = 0; b < nbatch; ++b) {
    const int base = lo + (b << 6);
    // phase 1: token indices + token loads (streamed, L1-hot)
    int idx[8], tok[8];
#pragma unroll
    for (int u = 0; u < 8; ++u) {
      idx[u] = base + 8 * u + g;
      tok[u] = tokens[min(idx[u], last)];
    }
    // phase 2: 8 scale loads (L2-resident) + 8 random 128B row loads
    float sv[8];
    uint4 rv[8];
#pragma unroll
    for (int u = 0; u < 8; ++u) {
      sv[u] = (idx[u] <= last) ? scales[tok[u]] : 0.f;
      rv[u] = *reinterpret_cast<const uint4*>(
          qtab + (size_t)tok[u] * DIM + c16);
    }
    // phase 3: decode + accumulate (masked rows have sv=0)
#pragma unroll
    for (int u = 0; u < 8; ++u) {
      ACC4(rv[u].x, 0, sv[u])
      ACC4(rv[u].y, 4, sv[u])
      ACC4(rv[u].z, 8, sv[u])
      ACC4(rv[u].w, 12, sv[u])
    }
  }
#pragma unroll
  for (int i = 0; i < 16; ++i) {
    acc[i] += __shfl_xor(acc[i], 8);
    acc[i] += __shfl_xor(acc[i], 16);
    acc[i] += __shfl_xor(acc[i], 32);
  }
  if (g == 0) {
    const int d0 = (lane & 7) * 16;
    float* op = out + (size_t)seg * DIM + d0;
    const float* bp = bias + d0;
#pragma unroll
    for (int j = 0; j < 4; ++j) {
      const float4 bv = *reinterpret_cast<const float4*>(bp + 4 * j);
      float4 o;
      o.x = fmaxf(acc[4 * j + 0] + bv.x, 0.f);
      o.y = fmaxf(acc[4 * j + 1] + bv.y, 0.f);
      o.z = fmaxf(acc[4 * j + 2] + bv.z, 0.f);
      o.w = fmaxf(acc[4 * j + 3] + bv.w, 0.f);
      *reinterpret_cast<float4*>(op + 4 * j) = o;
    }
  }
}
#undef ACC4

// =================== fp32 fallback path (ws too small) ====================
__global__ __launch_bounds__(256) void boundaries_kernel(
    const int* __restrict__ segs, int* __restrict__ seg_start, int T, int B) {
  const int i = blockIdx.x * 256 + threadIdx.x;
  if (i > T) return;
  const int cur = (i < T) ? segs[i] : B;
  const int prev = (i > 0) ? segs[i - 1] : -1;
  for (int s = prev + 1; s <= cur; ++s) seg_start[s] = i;
}

#define LOADF(u, TIDX)                                                     \
  const int t##u = tokens[(TIDX)];                                         \
  const float4 e##u = *reinterpret_cast<const float4*>(                    \
      emb + (size_t)t##u * DIM + c4);
#define ADDF(u) { acc.x += e##u.x; acc.y += e##u.y; acc.z += e##u.z; acc.w += e##u.w; }

__global__ __launch_bounds__(256, 4) void segsum_f32(
    const int* __restrict__ tokens, const float* __restrict__ emb,
    const int* __restrict__ seg_start, float* __restrict__ bow, int B) {
  const int seg = blockIdx.x * 4 + (threadIdx.x >> 6);
  if (seg >= B) return;
  const int lane = threadIdx.x & 63;
  const int half = lane >> 5;
  const int c4 = (lane & 31) * 4;
  const int lo = seg_start[seg], hi = seg_start[seg + 1];
  const int cnt = hi - lo;
  float4 acc = make_float4(0.f, 0.f, 0.f, 0.f);

  int base = lo;
  const int nb = cnt >> 4;
  for (int b = 0; b < nb; ++b, base += 16) {
    LOADF(0, base + 0 + half)  LOADF(1, base + 2 + half)
    LOADF(2, base + 4 + half)  LOADF(3, base + 6 + half)
    LOADF(4, base + 8 + half)  LOADF(5, base + 10 + half)
    LOADF(6, base + 12 + half) LOADF(7, base + 14 + half)
    ADDF(0) ADDF(1) ADDF(2) ADDF(3) ADDF(4) ADDF(5) ADDF(6) ADDF(7)
  }
  if (cnt & 15) {
    const int last = hi - 1;
#define LOADT(u) const int i##u = base + 2 * u + half; LOADF(u, min(i##u, last))
    LOADT(0) LOADT(1) LOADT(2) LOADT(3)
    LOADT(4) LOADT(5) LOADT(6) LOADT(7)
    if (i0 <= last) ADDF(0)
    if (i1 <= last) ADDF(1)
    if (i2 <= last) ADDF(2)
    if (i3 <= last) ADDF(3)
    if (i4 <= last) ADDF(4)
    if (i5 <= last) ADDF(5)
    if (i6 <= last) ADDF(6)
    if (i7 <= last) ADDF(7)
#undef LOADT
  }
  acc.x += __shfl_xor(acc.x, 32);
  acc.y += __shfl_xor(acc.y, 32);
  acc.z += __shfl_xor(acc.z, 32);
  acc.w += __shfl_xor(acc.w, 32);
  if (half == 0)
    *reinterpret_cast<float4*>(bow + (size_t)seg * DIM + c4) = acc;
}

// out = relu(bow @ W + b), in-place over d_out (fallback only)
__global__ __launch_bounds__(256) void gemm_bias_relu(
    const float* __restrict__ bow, const float* __restrict__ W,
    const float* __restrict__ bias, float* __restrict__ out) {
  __shared__ float bt[GROWS][DIM];
  const int tid = threadIdx.x;
  const size_t row0 = (size_t)blockIdx.x * GROWS;

  {
    const float4* src = reinterpret_cast<const float4*>(bow + row0 * DIM);
    float4* dst = reinterpret_cast<float4*>(&bt[0][0]);
#pragma unroll
    for (int i = 0; i < (GROWS * DIM / 4) / 256; ++i)
      dst[tid + 256 * i] = src[tid + 256 * i];
  }
  __syncthreads();

  const int cg = tid & 31;
  const int rg = tid >> 5;
  const int c0 = cg * 4;

  float acc[4][4] = {};
#pragma unroll 4
  for (int k = 0; k < DIM; ++k) {
    const float4 w4 = *reinterpret_cast<const float4*>(W + (size_t)k * DIM + c0);
#pragma unroll
    for (int j = 0; j < 4; ++j) {
      const float s = bt[rg * 4 + j][k];
      acc[j][0] = fmaf(s, w4.x, acc[j][0]);
      acc[j][1] = fmaf(s, w4.y, acc[j][1]);
      acc[j][2] = fmaf(s, w4.z, acc[j][2]);
      acc[j][3] = fmaf(s, w4.w, acc[j][3]);
    }
  }

  const float4 bv = *reinterpret_cast<const float4*>(bias + c0);
#pragma unroll
  for (int j = 0; j < 4; ++j) {
    float4 o;
    o.x = fmaxf(acc[j][0] + bv.x, 0.f);
    o.y = fmaxf(acc[j][1] + bv.y, 0.f);
    o.z = fmaxf(acc[j][2] + bv.z, 0.f);
    o.w = fmaxf(acc[j][3] + bv.w, 0.f);
    *reinterpret_cast<float4*>(out + (row0 + rg * 4 + j) * DIM + c0) = o;
  }
}

extern "C" void kernel_launch(void* const* d_in, const int* in_sizes, int n_in,
                              void* d_out, int out_size, void* d_ws, size_t ws_size,
                              hipStream_t stream) {
  const int* tokens = (const int*)d_in[0];
  const int* segs = (const int*)d_in[1];
  const float* emb = (const float*)d_in[2];
  const float* W = (const float*)d_in[3];
  const float* bias = (const float*)d_in[4];
  float* out = (float*)d_out;

  const int T = in_sizes[0];
  const int B = out_size / DIM;       // 16384
  const int V = in_sizes[2] / DIM;    // 100000

  int* seg_start = (int*)d_ws;                       // (B+1) ints
  const size_t ss_bytes = ((size_t)(B + 1) * 4 + 255) & ~(size_t)255;
  const size_t sc_bytes = ((size_t)V * 4 + 255) & ~(size_t)255;

  const bool qok = ws_size >= ss_bytes + sc_bytes + (size_t)V * DIM;
  if (qok) {
    float* scales = (float*)((char*)d_ws + ss_bytes);
    signed char* qtab = (signed char*)((char*)d_ws + ss_bytes + sc_bytes);
    const int nbBound = (T + 1 + 255) / 256;
    const int NTRANS = 512;                          // transform blocks
    const int mtiles = V / 16;
    prep_kernel<<<NTRANS + nbBound, 256, 0, stream>>>(
        segs, seg_start, emb, W, qtab, scales, T, B, V, mtiles, NTRANS);
    segsum_q8<<<(B + 3) / 4, 256, 0, stream>>>(
        tokens, qtab, scales, seg_start, bias, out, B);
  } else {
    float* bow = out;                                // in-place: gather -> GEMM
    boundaries_kernel<<<(T + 1 + 255) / 256, 256, 0, stream>>>(segs, seg_start, T, B);
    segsum_f32<<<(B + 3) / 4, 256, 0, stream>>>(tokens, emb, seg_start, bow, B);
    gemm_bias_relu<<<B / GROWS, 256, 0, stream>>>(bow, W, bias, out);
  }
}